// Round 3
// baseline (819.892 us; speedup 1.0000x reference)
//
#include <hip/hip_runtime.h>

#define NN 170000
#define NE 1200000
#define F_IN 128
#define F_HID 256
#define F_OUT 40
#define BN_EPS 1e-5f
#define SCAN_B ((NN + 255) / 256)
#define GB64 ((NN + 63) / 64)
#define STAT_ROWS GB64                               // one stat row per block
#define STAT_CHUNK 32
#define STAT_NCH ((STAT_ROWS + STAT_CHUNK - 1) / STAT_CHUNK)

typedef __attribute__((ext_vector_type(8))) short short8;
typedef __attribute__((ext_vector_type(4))) float f32x4;
typedef __attribute__((ext_vector_type(4))) unsigned short us4;
typedef __attribute__((ext_vector_type(4))) unsigned int u32x4;

// ---------------- bf16 helpers (manual, RNE) ----------------
__device__ __forceinline__ float b2f(unsigned short u) {
    union { unsigned x; float f; } c; c.x = ((unsigned)u) << 16; return c.f;
}
__device__ __forceinline__ unsigned short f2b(float f) {
    union { float f; unsigned x; } c; c.f = f;
    unsigned r = (c.x + 0x7FFFu + ((c.x >> 16) & 1u)) >> 16;
    return (unsigned short)r;
}

// 16B of bf16 (8 vals) accumulate into f32[8]
__device__ __forceinline__ void agg_sum(const u32x4& v, float (&aa)[8]) {
    aa[0] += b2f((unsigned short)(v.x & 0xffffu)); aa[1] += b2f((unsigned short)(v.x >> 16));
    aa[2] += b2f((unsigned short)(v.y & 0xffffu)); aa[3] += b2f((unsigned short)(v.y >> 16));
    aa[4] += b2f((unsigned short)(v.z & 0xffffu)); aa[5] += b2f((unsigned short)(v.z >> 16));
    aa[6] += b2f((unsigned short)(v.w & 0xffffu)); aa[7] += b2f((unsigned short)(v.w >> 16));
}
// fused BN+ReLU+norm_src per neighbor (f32), then accumulate
__device__ __forceinline__ void agg_fuse(const u32x4& v, float ns,
        const f32x4& ca0, const f32x4& ca1, const f32x4& cb0, const f32x4& cb1, float (&aa)[8]) {
    aa[0] += fmaxf(fmaf(b2f((unsigned short)(v.x & 0xffffu)), ca0.x, cb0.x), 0.f) * ns;
    aa[1] += fmaxf(fmaf(b2f((unsigned short)(v.x >> 16)),     ca0.y, cb0.y), 0.f) * ns;
    aa[2] += fmaxf(fmaf(b2f((unsigned short)(v.y & 0xffffu)), ca0.z, cb0.z), 0.f) * ns;
    aa[3] += fmaxf(fmaf(b2f((unsigned short)(v.y >> 16)),     ca0.w, cb0.w), 0.f) * ns;
    aa[4] += fmaxf(fmaf(b2f((unsigned short)(v.z & 0xffffu)), ca1.x, cb1.x), 0.f) * ns;
    aa[5] += fmaxf(fmaf(b2f((unsigned short)(v.z >> 16)),     ca1.y, cb1.y), 0.f) * ns;
    aa[6] += fmaxf(fmaf(b2f((unsigned short)(v.w & 0xffffu)), ca1.z, cb1.z), 0.f) * ns;
    aa[7] += fmaxf(fmaf(b2f((unsigned short)(v.w >> 16)),     ca1.w, cb1.w), 0.f) * ns;
}

// ---------------- CSR construction ----------------
__global__ void count_kernel(const int* __restrict__ src, const int* __restrict__ dst,
                             int* __restrict__ cnt_src, int* __restrict__ cnt_dst, int E) {
    int e = blockIdx.x * blockDim.x + threadIdx.x;
    if (e < E) {
        atomicAdd(&cnt_src[src[e]], 1);
        atomicAdd(&cnt_dst[dst[e]], 1);
    }
}

__global__ void norm_kernel(const int* __restrict__ cnt_src, const int* __restrict__ cnt_dst,
                            float* __restrict__ norm_src, float* __restrict__ norm_dst, int N) {
    int i = blockIdx.x * blockDim.x + threadIdx.x;
    if (i < N) {
        norm_src[i] = rsqrtf((float)max(cnt_src[i], 1));
        norm_dst[i] = rsqrtf((float)max(cnt_dst[i], 1));
    }
}

__global__ void scan_block_kernel(const int* __restrict__ cnt, int* __restrict__ local,
                                  int* __restrict__ partials, int N) {
    __shared__ int s[256];
    int t = threadIdx.x;
    int idx = blockIdx.x * 256 + t;
    int v = (idx < N) ? cnt[idx] : 0;
    s[t] = v;
    __syncthreads();
    #pragma unroll
    for (int off = 1; off < 256; off <<= 1) {
        int x = (t >= off) ? s[t - off] : 0;
        __syncthreads();
        s[t] += x;
        __syncthreads();
    }
    if (idx < N) local[idx] = s[t] - v;
    if (t == 255) partials[blockIdx.x] = s[t];
}

__global__ void scan_partials_kernel(int* __restrict__ partials, int B) {
    __shared__ int s[1024];
    int t = threadIdx.x;
    int v = (t < B) ? partials[t] : 0;
    s[t] = v;
    __syncthreads();
    #pragma unroll
    for (int off = 1; off < 1024; off <<= 1) {
        int x = (t >= off) ? s[t - off] : 0;
        __syncthreads();
        s[t] += x;
        __syncthreads();
    }
    if (t < B) partials[t] = s[t] - v;
}

__global__ void scan_add_kernel(const int* __restrict__ local, const int* __restrict__ partials,
                                int* __restrict__ row_ptr, int N) {
    int idx = blockIdx.x * blockDim.x + threadIdx.x;
    if (idx < N) row_ptr[idx] = local[idx] + partials[idx >> 8];
    if (idx == 0) row_ptr[N] = NE;
}

__global__ void fill_kernel(const int* __restrict__ src, const int* __restrict__ dst,
                            const int* __restrict__ row_ptr, int* __restrict__ fill,
                            int* __restrict__ csr_src, int E) {
    int e = blockIdx.x * blockDim.x + threadIdx.x;
    if (e < E) {
        int d = dst[e];
        int pos = row_ptr[d] + atomicAdd(&fill[d], 1);
        csr_src[pos] = src[e];
    }
}

// ---------------- feat f32 -> bf16, pre-scaled by norm_src[row] ----------------
__global__ void cast_feat_kernel(const float* __restrict__ feat, const float* __restrict__ norm_src,
                                 unsigned short* __restrict__ featb) {
    unsigned idx = blockIdx.x * blockDim.x + threadIdx.x;
    if (idx >= (unsigned)NN * (F_IN / 4)) return;
    float ns = norm_src[idx / (F_IN / 4)];
    f32x4 v = __builtin_nontemporal_load((const f32x4*)(feat + (size_t)idx * 4));
    us4 o; o.x = f2b(v.x * ns); o.y = f2b(v.y * ns); o.z = f2b(v.z * ns); o.w = f2b(v.w * ns);
    *(us4*)(featb + (size_t)idx * 4) = o;
}

// ---------------- weight transpose+cast: W[K][M] f32 -> Wt[MP][K] bf16 (zero-pad m>=M) ----
template<int K, int M, int MP>
__global__ void wt_kernel(const float* __restrict__ W, unsigned short* __restrict__ Wt) {
    int idx = blockIdx.x * blockDim.x + threadIdx.x;
    if (idx >= MP * K) return;
    int m = idx / K, k = idx % K;
    float v = (m < M) ? W[(size_t)k * M + m] : 0.0f;
    Wt[idx] = f2b(v);
}

// ---------------- BN stats: tree reduce of per-block partials ----------------
// part layout: [STAT_ROWS][512] f32, row = blockIdx.x; cols 0..255 = sum, 256..511 = sumsq.
// Every slot is written unconditionally by the fused kernel, so no memset needed.
__global__ void stat_reduce_kernel(const float* __restrict__ part, float* __restrict__ red) {
    int c = threadIdx.x;                 // 0..511
    int ch = blockIdx.x;
    int r0 = ch * STAT_CHUNK;
    int r1 = min(r0 + STAT_CHUNK, STAT_ROWS);
    float s = 0.f;
    for (int r = r0; r < r1; r++) s += part[(size_t)r * 512 + c];
    red[ch * 512 + c] = s;
}

__global__ void bn_finalize2_kernel(const float* __restrict__ red,
                                    const float* __restrict__ gamma, const float* __restrict__ beta,
                                    float* __restrict__ a, float* __restrict__ b) {
    int c = threadIdx.x;                 // 0..255
    float sum = 0.f, sumsq = 0.f;
    for (int ch = 0; ch < STAT_NCH; ch++) {
        sum   += red[ch * 512 + c];
        sumsq += red[ch * 512 + 256 + c];
    }
    float invN = 1.0f / (float)NN;
    float mean = sum * invN;
    float var = sumsq * invN - mean * mean;
    float inv = rsqrtf(var + BN_EPS);
    float ac = inv * gamma[c];
    a[c] = ac;
    b[c] = beta[c] - mean * ac;
}

// ---------------- fused gather + MFMA GEMM (one GraphConv layer) ----------------
// R10: standalone tall-skinny GEMMs are latency/ramp-bound at ~185 TF no matter the schedule
// (R8 LDS-lockstep == R9 barrier-free direct-reg, both ~122us with all pipes idle). Fusing
// aggregation+projection deletes an 87MB write + 87MB read per layer and hides MFMA under
// the gather's memory latency (blocks in different phases overlap on a CU).
// Per block: 64 nodes. Phase 1: each wave gathers 16 nodes (subgroups of F/8 lanes, 16B/lane,
// f32 accumulate, optional per-neighbor BN+ReLU+norm_src), writes bf16 rows into XOR-swizzled
// LDS ( byte ^= (row&7)<<4 : 16-way bank conflict -> 2-way(free) on both write and b128 read).
// Phase 2: one barrier, then 16x16x32 MFMA of As vs Wt (L2-hot), epilogue x norm_dst,
// stats partials (plain stores) or +bias f32 final output.
template<int F, int WM_T, int WN_T, int WAVES_N, bool FUSE, bool LAST>
__global__ __launch_bounds__(256) void fused_gather_gemm(
        const unsigned short* __restrict__ h,          // N x F bf16 input rows
        const int* __restrict__ row_ptr, const int* __restrict__ csr_src,
        const float* __restrict__ bna, const float* __restrict__ bnb,
        const unsigned short* __restrict__ Wt,         // [MP][F] bf16
        const float* __restrict__ norm_src, const float* __restrict__ norm_dst,
        const float* __restrict__ bias,
        void* __restrict__ C, float* __restrict__ opart, int N) {
    constexpr int BM = 64;
    constexpr int LPN = F / 8;        // lanes per node (16B slices)
    constexpr int NPW = 64 / LPN;     // nodes gathered concurrently per wave
    constexpr int WAVES_M = 4 / WAVES_N;
    __shared__ unsigned short As[BM * F];

    const int lane = threadIdx.x & 63;
    const int wave = threadIdx.x >> 6;
    const int r0 = blockIdx.x * BM;

    // ---- phase 1: gather 16 nodes per wave into As ----
    {
        const int sub = lane / LPN;
        const int cl = lane % LPN;
        f32x4 ca0 = {0,0,0,0}, ca1 = {0,0,0,0}, cb0 = {0,0,0,0}, cb1 = {0,0,0,0};
        if (FUSE) {
            ca0 = *(const f32x4*)(bna + cl * 8);
            ca1 = *(const f32x4*)(bna + cl * 8 + 4);
            cb0 = *(const f32x4*)(bnb + cl * 8);
            cb1 = *(const f32x4*)(bnb + cl * 8 + 4);
        }
        #pragma unroll
        for (int g = 0; g < 16 / NPW; g++) {
            int nl = wave * 16 + g * NPW + sub;
            int node = r0 + nl;
            float aa[8] = {0.f, 0.f, 0.f, 0.f, 0.f, 0.f, 0.f, 0.f};
            int beg = 0, end = 0;
            if (node < N) { beg = row_ptr[node]; end = row_ptr[node + 1]; }
            int e = beg;
            for (; e + 2 <= end; e += 2) {
                int s0 = csr_src[e], s1 = csr_src[e + 1];
                u32x4 v0 = *(const u32x4*)(h + (size_t)s0 * F + cl * 8);
                u32x4 v1 = *(const u32x4*)(h + (size_t)s1 * F + cl * 8);
                if (FUSE) {
                    agg_fuse(v0, norm_src[s0], ca0, ca1, cb0, cb1, aa);
                    agg_fuse(v1, norm_src[s1], ca0, ca1, cb0, cb1, aa);
                } else {
                    agg_sum(v0, aa); agg_sum(v1, aa);
                }
            }
            if (e < end) {
                int s0 = csr_src[e];
                u32x4 v0 = *(const u32x4*)(h + (size_t)s0 * F + cl * 8);
                if (FUSE) agg_fuse(v0, norm_src[s0], ca0, ca1, cb0, cb1, aa);
                else      agg_sum(v0, aa);
            }
            u32x4 d;
            d.x = (unsigned)f2b(aa[0]) | ((unsigned)f2b(aa[1]) << 16);
            d.y = (unsigned)f2b(aa[2]) | ((unsigned)f2b(aa[3]) << 16);
            d.z = (unsigned)f2b(aa[4]) | ((unsigned)f2b(aa[5]) << 16);
            d.w = (unsigned)f2b(aa[6]) | ((unsigned)f2b(aa[7]) << 16);
            unsigned off = ((unsigned)(nl * (F * 2) + cl * 16)) ^ (((unsigned)nl & 7u) << 4);
            *(u32x4*)((char*)As + off) = d;
        }
    }
    __syncthreads();

    // ---- phase 2: MFMA As (LDS) x Wt (L2) ----
    const int quad = lane >> 4, l15 = lane & 15;
    const int wr = wave / WAVES_N, wc = wave % WAVES_N;
    const int wmb = wr * WM_T * 16;
    const int wnb = wc * WN_T * 16;

    const unsigned short* bptr[WN_T];
    #pragma unroll
    for (int j = 0; j < WN_T; j++)
        bptr[j] = Wt + (size_t)(wnb + j * 16 + l15) * F + quad * 8;

    f32x4 acc[WM_T][WN_T] = {};
    #pragma unroll
    for (int kk = 0; kk < F; kk += 32) {
        short8 af[WM_T], bf[WN_T];
        #pragma unroll
        for (int i = 0; i < WM_T; i++) {
            int row = wmb + i * 16 + l15;
            unsigned off = ((unsigned)(row * (F * 2) + (kk + quad * 8) * 2)) ^ (((unsigned)row & 7u) << 4);
            af[i] = *(const short8*)((const char*)As + off);
        }
        #pragma unroll
        for (int j = 0; j < WN_T; j++)
            bf[j] = *(const short8*)(bptr[j] + kk);
        #pragma unroll
        for (int i = 0; i < WM_T; i++)
            #pragma unroll
            for (int j = 0; j < WN_T; j++)
                acc[i][j] = __builtin_amdgcn_mfma_f32_16x16x32_bf16(af[i], bf[j], acc[i][j], 0, 0, 0);
    }

    // ---- epilogue: C/D layout col=lane&15, row=quad*4+reg ----
    float s[WN_T] = {}, ss[WN_T] = {};
    #pragma unroll
    for (int i = 0; i < WM_T; i++) {
        #pragma unroll
        for (int r = 0; r < 4; r++) {
            int row = r0 + wmb + i * 16 + quad * 4 + r;
            if (row >= N) continue;
            float nd = norm_dst[row];
            #pragma unroll
            for (int j = 0; j < WN_T; j++) {
                float v = acc[i][j][r] * nd;
                int col = wnb + j * 16 + l15;
                if (LAST) {
                    if (col < F_OUT)
                        ((float*)C)[(size_t)row * F_OUT + col] = v + bias[col];
                } else {
                    s[j] += v; ss[j] += v * v;
                    ((unsigned short*)C)[(size_t)row * F_HID + col] = f2b(v);
                }
            }
        }
    }
    if (!LAST) {
        #pragma unroll
        for (int j = 0; j < WN_T; j++) {
            float t = s[j], t2 = ss[j];
            t  += __shfl_xor(t, 16);  t  += __shfl_xor(t, 32);
            t2 += __shfl_xor(t2, 16); t2 += __shfl_xor(t2, 32);
            if (quad == 0) {
                int col = wnb + j * 16 + l15;
                size_t prow = (size_t)(blockIdx.x * WAVES_M + wr) * 512;
                opart[prow + col] = t;
                opart[prow + 256 + col] = t2;
            }
        }
    }
}

extern "C" void kernel_launch(void* const* d_in, const int* in_sizes, int n_in,
                              void* d_out, int out_size, void* d_ws, size_t ws_size,
                              hipStream_t stream) {
    const float* feat  = (const float*)d_in[0];
    const int*   src   = (const int*)d_in[1];
    const int*   dst   = (const int*)d_in[2];
    const float* W0    = (const float*)d_in[3];
    const float* W1    = (const float*)d_in[4];
    const float* W2    = (const float*)d_in[5];
    const float* b2    = (const float*)d_in[6];
    const float* g0    = (const float*)d_in[7];
    const float* beta0 = (const float*)d_in[8];
    const float* g1    = (const float*)d_in[9];
    const float* beta1 = (const float*)d_in[10];
    float* out = (float*)d_out;

    const int N = NN, E = NE;

    // ---- workspace carve (~231 MB; proven budget >= 268 MB)
    char* ws = (char*)d_ws;
    auto alloc_b = [&](size_t bytes) {
        void* p = (void*)ws;
        ws += ((bytes + 255) / 256) * 256;
        return p;
    };
    float* norm_src = (float*)alloc_b((size_t)N * 4);
    float* norm_dst = (float*)alloc_b((size_t)N * 4);
    int*   row_ptr  = (int*)alloc_b((size_t)(N + 1) * 4);
    int*   csr_src  = (int*)alloc_b((size_t)E * 4);
    float* bnpart   = (float*)alloc_b((size_t)STAT_ROWS * 512 * 4);   // 5.44 MB per-block partials
    float* bnred    = (float*)alloc_b((size_t)STAT_NCH * 512 * 4);    // 172 KB chunk partials
    float* bn_a0    = (float*)alloc_b(256 * 4);
    float* bn_b0    = (float*)alloc_b(256 * 4);
    float* bn_a1    = (float*)alloc_b(256 * 4);
    float* bn_b1    = (float*)alloc_b(256 * 4);
    unsigned short* Wt0 = (unsigned short*)alloc_b((size_t)256 * 128 * 2);
    unsigned short* Wt1 = (unsigned short*)alloc_b((size_t)256 * 256 * 2);
    unsigned short* Wt2 = (unsigned short*)alloc_b((size_t)64 * 256 * 2);
    void* B1 = alloc_b((size_t)N * 512);   // N x 256 bf16
    void* B2 = alloc_b((size_t)N * 512);
    unsigned short* featb = (unsigned short*)alloc_b((size_t)N * F_IN * 2);

    unsigned short* B1b = (unsigned short*)B1;
    unsigned short* B2b = (unsigned short*)B2;

    // CSR-build scratch aliased at head of B1 (dead before fused0 writes B1)
    int* cnt_src  = (int*)B1;
    int* cnt_dst  = cnt_src + N;
    int* fill     = cnt_dst + N;
    int* local    = fill + N;
    int* partials = local + N;

    // ---- CSR build + norms + weight prep + feat cast (pre-scaled by norm_src)
    hipMemsetAsync(cnt_src, 0, ((size_t)4 * N + 1024) * 4, stream);
    count_kernel<<<(E + 255) / 256, 256, 0, stream>>>(src, dst, cnt_src, cnt_dst, E);
    norm_kernel<<<(N + 255) / 256, 256, 0, stream>>>(cnt_src, cnt_dst, norm_src, norm_dst, N);
    scan_block_kernel<<<SCAN_B, 256, 0, stream>>>(cnt_dst, local, partials, N);
    scan_partials_kernel<<<1, 1024, 0, stream>>>(partials, SCAN_B);
    scan_add_kernel<<<(N + 255) / 256, 256, 0, stream>>>(local, partials, row_ptr, N);
    fill_kernel<<<(E + 255) / 256, 256, 0, stream>>>(src, dst, row_ptr, fill, csr_src, E);
    wt_kernel<128, 256, 256><<<(256 * 128 + 255) / 256, 256, 0, stream>>>(W0, Wt0);
    wt_kernel<256, 256, 256><<<(256 * 256 + 255) / 256, 256, 0, stream>>>(W1, Wt1);
    wt_kernel<256, 40, 64><<<(64 * 256 + 255) / 256, 256, 0, stream>>>(W2, Wt2);
    cast_feat_kernel<<<((unsigned)N * (F_IN / 4) + 255) / 256, 256, 0, stream>>>(feat, norm_src, featb);

    // ---- layer 0: fused gather(sum) + GEMM0 (x norm_dst, stats) featb -> B1
    fused_gather_gemm<128, 4, 4, 4, false, false><<<GB64, 256, 0, stream>>>(
        featb, row_ptr, csr_src, nullptr, nullptr, Wt0, nullptr, norm_dst, nullptr, B1, bnpart, N);
    stat_reduce_kernel<<<STAT_NCH, 512, 0, stream>>>(bnpart, bnred);
    bn_finalize2_kernel<<<1, 256, 0, stream>>>(bnred, g0, beta0, bn_a0, bn_b0);

    // ---- layer 1: fused gather(BN0+ReLU+norm_src) + GEMM1 (x norm_dst, stats) B1 -> B2
    fused_gather_gemm<256, 4, 4, 4, true, false><<<GB64, 256, 0, stream>>>(
        B1b, row_ptr, csr_src, bn_a0, bn_b0, Wt1, norm_src, norm_dst, nullptr, B2, bnpart, N);
    stat_reduce_kernel<<<STAT_NCH, 512, 0, stream>>>(bnpart, bnred);
    bn_finalize2_kernel<<<1, 256, 0, stream>>>(bnred, g1, beta1, bn_a1, bn_b1);

    // ---- layer 2: fused gather(BN1+ReLU+norm_src) + GEMM2 (x norm_dst, +bias) B2 -> out (f32)
    fused_gather_gemm<256, 1, 3, 1, true, true><<<GB64, 256, 0, stream>>>(
        B2b, row_ptr, csr_src, bn_a1, bn_b1, Wt2, norm_src, norm_dst, b2, out, nullptr, N);
}

// Round 4
// 764.611 us; speedup vs baseline: 1.0723x; 1.0723x over previous
//
#include <hip/hip_runtime.h>

#define NN 170000
#define NE 1200000
#define F_IN 128
#define F_HID 256
#define F_OUT 40
#define BN_EPS 1e-5f
#define SCAN_B ((NN + 255) / 256)
#define GB64 ((NN + 63) / 64)
#define GB128 ((NN + 127) / 128)
#define STAT_ROWS GB64                               // one stat row per block
#define STAT_CHUNK 32
#define STAT_NCH ((STAT_ROWS + STAT_CHUNK - 1) / STAT_CHUNK)

typedef __attribute__((ext_vector_type(8))) short short8;
typedef __attribute__((ext_vector_type(4))) float f32x4;
typedef __attribute__((ext_vector_type(4))) unsigned short us4;
typedef __attribute__((ext_vector_type(4))) unsigned int u32x4;

// ---------------- bf16 helpers (manual, RNE) ----------------
__device__ __forceinline__ float b2f(unsigned short u) {
    union { unsigned x; float f; } c; c.x = ((unsigned)u) << 16; return c.f;
}
__device__ __forceinline__ unsigned short f2b(float f) {
    union { float f; unsigned x; } c; c.f = f;
    unsigned r = (c.x + 0x7FFFu + ((c.x >> 16) & 1u)) >> 16;
    return (unsigned short)r;
}
// BN+ReLU two packed bf16 lanes of one uint
__device__ __forceinline__ unsigned bn2(unsigned u, float a0, float b0, float a1, float b1) {
    float lo = b2f((unsigned short)(u & 0xffffu));
    float hi = b2f((unsigned short)(u >> 16));
    lo = fmaxf(lo * a0 + b0, 0.0f);
    hi = fmaxf(hi * a1 + b1, 0.0f);
    return (unsigned)f2b(lo) | ((unsigned)f2b(hi) << 16);
}

// 16B of bf16 (8 vals) accumulate into f32[8]
__device__ __forceinline__ void agg_sum(const u32x4& v, float (&aa)[8]) {
    aa[0] += b2f((unsigned short)(v.x & 0xffffu)); aa[1] += b2f((unsigned short)(v.x >> 16));
    aa[2] += b2f((unsigned short)(v.y & 0xffffu)); aa[3] += b2f((unsigned short)(v.y >> 16));
    aa[4] += b2f((unsigned short)(v.z & 0xffffu)); aa[5] += b2f((unsigned short)(v.z >> 16));
    aa[6] += b2f((unsigned short)(v.w & 0xffffu)); aa[7] += b2f((unsigned short)(v.w >> 16));
}
// fused BN+ReLU+norm_src per neighbor (f32), then accumulate
__device__ __forceinline__ void agg_fuse(const u32x4& v, float ns,
        const f32x4& ca0, const f32x4& ca1, const f32x4& cb0, const f32x4& cb1, float (&aa)[8]) {
    aa[0] += fmaxf(fmaf(b2f((unsigned short)(v.x & 0xffffu)), ca0.x, cb0.x), 0.f) * ns;
    aa[1] += fmaxf(fmaf(b2f((unsigned short)(v.x >> 16)),     ca0.y, cb0.y), 0.f) * ns;
    aa[2] += fmaxf(fmaf(b2f((unsigned short)(v.y & 0xffffu)), ca0.z, cb0.z), 0.f) * ns;
    aa[3] += fmaxf(fmaf(b2f((unsigned short)(v.y >> 16)),     ca0.w, cb0.w), 0.f) * ns;
    aa[4] += fmaxf(fmaf(b2f((unsigned short)(v.z & 0xffffu)), ca1.x, cb1.x), 0.f) * ns;
    aa[5] += fmaxf(fmaf(b2f((unsigned short)(v.z >> 16)),     ca1.y, cb1.y), 0.f) * ns;
    aa[6] += fmaxf(fmaf(b2f((unsigned short)(v.w & 0xffffu)), ca1.z, cb1.z), 0.f) * ns;
    aa[7] += fmaxf(fmaf(b2f((unsigned short)(v.w >> 16)),     ca1.w, cb1.w), 0.f) * ns;
}

// ---------------- CSR construction ----------------
__global__ void count_kernel(const int* __restrict__ src, const int* __restrict__ dst,
                             int* __restrict__ cnt_src, int* __restrict__ cnt_dst, int E) {
    int e = blockIdx.x * blockDim.x + threadIdx.x;
    if (e < E) {
        atomicAdd(&cnt_src[src[e]], 1);
        atomicAdd(&cnt_dst[dst[e]], 1);
    }
}

__global__ void norm_kernel(const int* __restrict__ cnt_src, const int* __restrict__ cnt_dst,
                            float* __restrict__ norm_src, float* __restrict__ norm_dst, int N) {
    int i = blockIdx.x * blockDim.x + threadIdx.x;
    if (i < N) {
        norm_src[i] = rsqrtf((float)max(cnt_src[i], 1));
        norm_dst[i] = rsqrtf((float)max(cnt_dst[i], 1));
    }
}

__global__ void scan_block_kernel(const int* __restrict__ cnt, int* __restrict__ local,
                                  int* __restrict__ partials, int N) {
    __shared__ int s[256];
    int t = threadIdx.x;
    int idx = blockIdx.x * 256 + t;
    int v = (idx < N) ? cnt[idx] : 0;
    s[t] = v;
    __syncthreads();
    #pragma unroll
    for (int off = 1; off < 256; off <<= 1) {
        int x = (t >= off) ? s[t - off] : 0;
        __syncthreads();
        s[t] += x;
        __syncthreads();
    }
    if (idx < N) local[idx] = s[t] - v;
    if (t == 255) partials[blockIdx.x] = s[t];
}

__global__ void scan_partials_kernel(int* __restrict__ partials, int B) {
    __shared__ int s[1024];
    int t = threadIdx.x;
    int v = (t < B) ? partials[t] : 0;
    s[t] = v;
    __syncthreads();
    #pragma unroll
    for (int off = 1; off < 1024; off <<= 1) {
        int x = (t >= off) ? s[t - off] : 0;
        __syncthreads();
        s[t] += x;
        __syncthreads();
    }
    if (t < B) partials[t] = s[t] - v;
}

__global__ void scan_add_kernel(const int* __restrict__ local, const int* __restrict__ partials,
                                int* __restrict__ row_ptr, int N) {
    int idx = blockIdx.x * blockDim.x + threadIdx.x;
    if (idx < N) row_ptr[idx] = local[idx] + partials[idx >> 8];
    if (idx == 0) row_ptr[N] = NE;
}

__global__ void fill_kernel(const int* __restrict__ src, const int* __restrict__ dst,
                            const int* __restrict__ row_ptr, int* __restrict__ fill,
                            int* __restrict__ csr_src, int E) {
    int e = blockIdx.x * blockDim.x + threadIdx.x;
    if (e < E) {
        int d = dst[e];
        int pos = row_ptr[d] + atomicAdd(&fill[d], 1);
        csr_src[pos] = src[e];
    }
}

// ---------------- feat f32 -> bf16, pre-scaled by norm_src[row] ----------------
__global__ void cast_feat_kernel(const float* __restrict__ feat, const float* __restrict__ norm_src,
                                 unsigned short* __restrict__ featb) {
    unsigned idx = blockIdx.x * blockDim.x + threadIdx.x;
    if (idx >= (unsigned)NN * (F_IN / 4)) return;
    float ns = norm_src[idx / (F_IN / 4)];
    f32x4 v = __builtin_nontemporal_load((const f32x4*)(feat + (size_t)idx * 4));
    us4 o; o.x = f2b(v.x * ns); o.y = f2b(v.y * ns); o.z = f2b(v.z * ns); o.w = f2b(v.w * ns);
    *(us4*)(featb + (size_t)idx * 4) = o;
}

// ---------------- weight transpose+cast: W[K][M] f32 -> Wt[MP][K] bf16 (zero-pad m>=M) ----
template<int K, int M, int MP>
__global__ void wt_kernel(const float* __restrict__ W, unsigned short* __restrict__ Wt) {
    int idx = blockIdx.x * blockDim.x + threadIdx.x;
    if (idx >= MP * K) return;
    int m = idx / K, k = idx % K;
    float v = (m < M) ? W[(size_t)k * M + m] : 0.0f;
    Wt[idx] = f2b(v);
}

// ---------------- BN stats: tree reduce of per-block partials ----------------
__global__ void stat_reduce_kernel(const float* __restrict__ part, float* __restrict__ red) {
    int c = threadIdx.x;                 // 0..511
    int ch = blockIdx.x;
    int r0 = ch * STAT_CHUNK;
    int r1 = min(r0 + STAT_CHUNK, STAT_ROWS);
    float s = 0.f;
    for (int r = r0; r < r1; r++) s += part[(size_t)r * 512 + c];
    red[ch * 512 + c] = s;
}

__global__ void bn_finalize2_kernel(const float* __restrict__ red,
                                    const float* __restrict__ gamma, const float* __restrict__ beta,
                                    float* __restrict__ a, float* __restrict__ b) {
    int c = threadIdx.x;                 // 0..255
    float sum = 0.f, sumsq = 0.f;
    for (int ch = 0; ch < STAT_NCH; ch++) {
        sum   += red[ch * 512 + c];
        sumsq += red[ch * 512 + 256 + c];
    }
    float invN = 1.0f / (float)NN;
    float mean = sum * invN;
    float var = sumsq * invN - mean * mean;
    float inv = rsqrtf(var + BN_EPS);
    float ac = inv * gamma[c];
    a[c] = ac;
    b[c] = beta[c] - mean * ac;
}

// ---------------- fused gather + MFMA GEMM (GraphConv layers 0 and 1) ----------------
// R10/R11: fusion pays where it is traffic-neutral (saves the 87MB x2 round-trip; fused1
// 210us < split 242us) but NOT for layer 2 (gather-first widened per-edge reads 160B->512B,
// regression). Layers 0/1 stay fused; layer 2 is project-first (gemm2 + gather_final below).
// R11: edge loop deepened to a 4/2/1 unroll ladder -- with mean degree ~7 and ~300-900cy
// random-row latency, 2 outstanding loads/lane was the gather's serializer (VALUBusy 32%,
// everything else idle).
template<int F, int WM_T, int WN_T, int WAVES_N, bool FUSE, bool LAST>
__global__ __launch_bounds__(256) void fused_gather_gemm(
        const unsigned short* __restrict__ h,          // N x F bf16 input rows
        const int* __restrict__ row_ptr, const int* __restrict__ csr_src,
        const float* __restrict__ bna, const float* __restrict__ bnb,
        const unsigned short* __restrict__ Wt,         // [MP][F] bf16
        const float* __restrict__ norm_src, const float* __restrict__ norm_dst,
        const float* __restrict__ bias,
        void* __restrict__ C, float* __restrict__ opart, int N) {
    constexpr int BM = 64;
    constexpr int LPN = F / 8;        // lanes per node (16B slices)
    constexpr int NPW = 64 / LPN;     // nodes gathered concurrently per wave
    constexpr int WAVES_M = 4 / WAVES_N;
    __shared__ unsigned short As[BM * F];

    const int lane = threadIdx.x & 63;
    const int wave = threadIdx.x >> 6;
    const int r0 = blockIdx.x * BM;

    // ---- phase 1: gather 16 nodes per wave into As ----
    {
        const int sub = lane / LPN;
        const int cl = lane % LPN;
        f32x4 ca0 = {0,0,0,0}, ca1 = {0,0,0,0}, cb0 = {0,0,0,0}, cb1 = {0,0,0,0};
        if (FUSE) {
            ca0 = *(const f32x4*)(bna + cl * 8);
            ca1 = *(const f32x4*)(bna + cl * 8 + 4);
            cb0 = *(const f32x4*)(bnb + cl * 8);
            cb1 = *(const f32x4*)(bnb + cl * 8 + 4);
        }
        #pragma unroll
        for (int g = 0; g < 16 / NPW; g++) {
            int nl = wave * 16 + g * NPW + sub;
            int node = r0 + nl;
            float aa[8] = {0.f, 0.f, 0.f, 0.f, 0.f, 0.f, 0.f, 0.f};
            int beg = 0, end = 0;
            if (node < N) { beg = row_ptr[node]; end = row_ptr[node + 1]; }
            int e = beg;
            for (; e + 4 <= end; e += 4) {
                int s0 = csr_src[e],     s1 = csr_src[e + 1];
                int s2 = csr_src[e + 2], s3 = csr_src[e + 3];
                u32x4 v0 = *(const u32x4*)(h + (size_t)s0 * F + cl * 8);
                u32x4 v1 = *(const u32x4*)(h + (size_t)s1 * F + cl * 8);
                u32x4 v2 = *(const u32x4*)(h + (size_t)s2 * F + cl * 8);
                u32x4 v3 = *(const u32x4*)(h + (size_t)s3 * F + cl * 8);
                if (FUSE) {
                    float n0 = norm_src[s0], n1 = norm_src[s1];
                    float n2 = norm_src[s2], n3 = norm_src[s3];
                    agg_fuse(v0, n0, ca0, ca1, cb0, cb1, aa);
                    agg_fuse(v1, n1, ca0, ca1, cb0, cb1, aa);
                    agg_fuse(v2, n2, ca0, ca1, cb0, cb1, aa);
                    agg_fuse(v3, n3, ca0, ca1, cb0, cb1, aa);
                } else {
                    agg_sum(v0, aa); agg_sum(v1, aa);
                    agg_sum(v2, aa); agg_sum(v3, aa);
                }
            }
            for (; e + 2 <= end; e += 2) {
                int s0 = csr_src[e], s1 = csr_src[e + 1];
                u32x4 v0 = *(const u32x4*)(h + (size_t)s0 * F + cl * 8);
                u32x4 v1 = *(const u32x4*)(h + (size_t)s1 * F + cl * 8);
                if (FUSE) {
                    float n0 = norm_src[s0], n1 = norm_src[s1];
                    agg_fuse(v0, n0, ca0, ca1, cb0, cb1, aa);
                    agg_fuse(v1, n1, ca0, ca1, cb0, cb1, aa);
                } else {
                    agg_sum(v0, aa); agg_sum(v1, aa);
                }
            }
            if (e < end) {
                int s0 = csr_src[e];
                u32x4 v0 = *(const u32x4*)(h + (size_t)s0 * F + cl * 8);
                if (FUSE) agg_fuse(v0, norm_src[s0], ca0, ca1, cb0, cb1, aa);
                else      agg_sum(v0, aa);
            }
            u32x4 d;
            d.x = (unsigned)f2b(aa[0]) | ((unsigned)f2b(aa[1]) << 16);
            d.y = (unsigned)f2b(aa[2]) | ((unsigned)f2b(aa[3]) << 16);
            d.z = (unsigned)f2b(aa[4]) | ((unsigned)f2b(aa[5]) << 16);
            d.w = (unsigned)f2b(aa[6]) | ((unsigned)f2b(aa[7]) << 16);
            unsigned off = ((unsigned)(nl * (F * 2) + cl * 16)) ^ (((unsigned)nl & 7u) << 4);
            *(u32x4*)((char*)As + off) = d;
        }
    }
    __syncthreads();

    // ---- phase 2: MFMA As (LDS) x Wt (L2) ----
    const int quad = lane >> 4, l15 = lane & 15;
    const int wr = wave / WAVES_N, wc = wave % WAVES_N;
    const int wmb = wr * WM_T * 16;
    const int wnb = wc * WN_T * 16;

    const unsigned short* bptr[WN_T];
    #pragma unroll
    for (int j = 0; j < WN_T; j++)
        bptr[j] = Wt + (size_t)(wnb + j * 16 + l15) * F + quad * 8;

    f32x4 acc[WM_T][WN_T] = {};
    #pragma unroll
    for (int kk = 0; kk < F; kk += 32) {
        short8 af[WM_T], bf[WN_T];
        #pragma unroll
        for (int i = 0; i < WM_T; i++) {
            int row = wmb + i * 16 + l15;
            unsigned off = ((unsigned)(row * (F * 2) + (kk + quad * 8) * 2)) ^ (((unsigned)row & 7u) << 4);
            af[i] = *(const short8*)((const char*)As + off);
        }
        #pragma unroll
        for (int j = 0; j < WN_T; j++)
            bf[j] = *(const short8*)(bptr[j] + kk);
        #pragma unroll
        for (int i = 0; i < WM_T; i++)
            #pragma unroll
            for (int j = 0; j < WN_T; j++)
                acc[i][j] = __builtin_amdgcn_mfma_f32_16x16x32_bf16(af[i], bf[j], acc[i][j], 0, 0, 0);
    }

    // ---- epilogue: C/D layout col=lane&15, row=quad*4+reg ----
    float s[WN_T] = {}, ss[WN_T] = {};
    #pragma unroll
    for (int i = 0; i < WM_T; i++) {
        #pragma unroll
        for (int r = 0; r < 4; r++) {
            int row = r0 + wmb + i * 16 + quad * 4 + r;
            if (row >= N) continue;
            float nd = norm_dst[row];
            #pragma unroll
            for (int j = 0; j < WN_T; j++) {
                float v = acc[i][j][r] * nd;
                int col = wnb + j * 16 + l15;
                if (LAST) {
                    if (col < F_OUT)
                        ((float*)C)[(size_t)row * F_OUT + col] = v + bias[col];
                } else {
                    s[j] += v; ss[j] += v * v;
                    ((unsigned short*)C)[(size_t)row * F_HID + col] = f2b(v);
                }
            }
        }
    }
    if (!LAST) {
        #pragma unroll
        for (int j = 0; j < WN_T; j++) {
            float t = s[j], t2 = ss[j];
            t  += __shfl_xor(t, 16);  t  += __shfl_xor(t, 32);
            t2 += __shfl_xor(t2, 16); t2 += __shfl_xor(t2, 32);
            if (quad == 0) {
                int col = wnb + j * 16 + l15;
                size_t prow = (size_t)(blockIdx.x * WAVES_M + wr) * 512;
                opart[prow + col] = t;
                opart[prow + 256 + col] = t2;
            }
        }
    }
}

// ---------------- layer-2 projection GEMM: barrier-free, direct-register ----------------
// x = norm_src .* relu(bn1(h1)); y_pre = x @ W2  (N x 40, f32). BN+ReLU applied on A-fragments,
// norm_src as epilogue row-scale (commutes with @W2 by linearity). No LDS, no barriers --
// proven R9 structure; fine at this size since the following gather is the narrow one.
__global__ __launch_bounds__(256, 3) void gemm2_kernel(const unsigned short* __restrict__ A,
                                                       const unsigned short* __restrict__ Wt,
                                                       const float* __restrict__ norm_src,
                                                       const float* __restrict__ bna,
                                                       const float* __restrict__ bnb,
                                                       float* __restrict__ C, int N) {
    constexpr int K = 256, WM_T = 2, WN_T = 4;
    const int lane = threadIdx.x & 63;
    const int wave = threadIdx.x >> 6;
    const int quad = lane >> 4, l15 = lane & 15;
    const int r0 = blockIdx.x * 128;
    const int wmb = wave * WM_T * 16;

    const unsigned short* aptr[WM_T];
    #pragma unroll
    for (int i = 0; i < WM_T; i++) {
        int gr = r0 + wmb + i * 16 + l15;
        if (gr > N - 1) gr = N - 1;
        aptr[i] = A + (size_t)gr * K + quad * 8;
    }
    const unsigned short* bptr[WN_T];
    #pragma unroll
    for (int j = 0; j < WN_T; j++)
        bptr[j] = Wt + (size_t)(j * 16 + l15) * K + quad * 8;

    f32x4 acc[WM_T][WN_T] = {};
    #pragma unroll
    for (int kk = 0; kk < K; kk += 32) {
        int kb = kk + quad * 8;
        const f32x4 a0 = *(const f32x4*)(bna + kb);
        const f32x4 a1 = *(const f32x4*)(bna + kb + 4);
        const f32x4 s0 = *(const f32x4*)(bnb + kb);
        const f32x4 s1 = *(const f32x4*)(bnb + kb + 4);
        short8 af[WM_T], bf[WN_T];
        #pragma unroll
        for (int i = 0; i < WM_T; i++) {
            u32x4 u = *(const u32x4*)(aptr[i] + kk);
            u.x = bn2(u.x, a0.x, s0.x, a0.y, s0.y);
            u.y = bn2(u.y, a0.z, s0.z, a0.w, s0.w);
            u.z = bn2(u.z, a1.x, s1.x, a1.y, s1.y);
            u.w = bn2(u.w, a1.z, s1.z, a1.w, s1.w);
            af[i] = *(short8*)&u;
        }
        #pragma unroll
        for (int j = 0; j < WN_T; j++)
            bf[j] = *(const short8*)(bptr[j] + kk);
        #pragma unroll
        for (int i = 0; i < WM_T; i++)
            #pragma unroll
            for (int j = 0; j < WN_T; j++)
                acc[i][j] = __builtin_amdgcn_mfma_f32_16x16x32_bf16(af[i], bf[j], acc[i][j], 0, 0, 0);
    }

    #pragma unroll
    for (int i = 0; i < WM_T; i++) {
        #pragma unroll
        for (int r = 0; r < 4; r++) {
            int row = r0 + wmb + i * 16 + quad * 4 + r;
            if (row >= N) continue;
            float ns = norm_src[row];
            #pragma unroll
            for (int j = 0; j < WN_T; j++) {
                int col = j * 16 + l15;
                if (col < F_OUT)
                    C[(size_t)row * F_OUT + col] = acc[i][j][r] * ns;
            }
        }
    }
}

// ---------------- final gather: f32 in (width 40, pre-scaled by norm_src) + nd + bias ----------
__global__ void gather_final_kernel(const float* __restrict__ h, const int* __restrict__ row_ptr,
                                    const int* __restrict__ csr_src,
                                    const float* __restrict__ norm_dst, const float* __restrict__ bias,
                                    float* __restrict__ out, int N) {
    constexpr int TPN = F_OUT / 4;
    unsigned idx = blockIdx.x * blockDim.x + threadIdx.x;
    if (idx >= (unsigned)N * TPN) return;
    unsigned node = idx / TPN;
    unsigned g = idx % TPN;
    int beg = row_ptr[node], end = row_ptr[node + 1];
    float ax0 = 0.f, ay0 = 0.f, az0 = 0.f, aw0 = 0.f;
    float ax1 = 0.f, ay1 = 0.f, az1 = 0.f, aw1 = 0.f;
    int e = beg;
    for (; e + 2 <= end; e += 2) {
        int s0 = csr_src[e], s1 = csr_src[e + 1];
        const f32x4 v0 = *(const f32x4*)(h + (size_t)s0 * F_OUT + g * 4);
        const f32x4 v1 = *(const f32x4*)(h + (size_t)s1 * F_OUT + g * 4);
        ax0 += v0.x; ay0 += v0.y; az0 += v0.z; aw0 += v0.w;
        ax1 += v1.x; ay1 += v1.y; az1 += v1.z; aw1 += v1.w;
    }
    if (e < end) {
        int s0 = csr_src[e];
        const f32x4 v0 = *(const f32x4*)(h + (size_t)s0 * F_OUT + g * 4);
        ax0 += v0.x; ay0 += v0.y; az0 += v0.z; aw0 += v0.w;
    }
    float nd = norm_dst[node];
    const f32x4 b = *(const f32x4*)(bias + g * 4);
    f32x4 r;
    r.x = (ax0 + ax1) * nd + b.x; r.y = (ay0 + ay1) * nd + b.y;
    r.z = (az0 + az1) * nd + b.z; r.w = (aw0 + aw1) * nd + b.w;
    __builtin_nontemporal_store(r, (f32x4*)(out + (size_t)node * F_OUT + g * 4));
}

extern "C" void kernel_launch(void* const* d_in, const int* in_sizes, int n_in,
                              void* d_out, int out_size, void* d_ws, size_t ws_size,
                              hipStream_t stream) {
    const float* feat  = (const float*)d_in[0];
    const int*   src   = (const int*)d_in[1];
    const int*   dst   = (const int*)d_in[2];
    const float* W0    = (const float*)d_in[3];
    const float* W1    = (const float*)d_in[4];
    const float* W2    = (const float*)d_in[5];
    const float* b2    = (const float*)d_in[6];
    const float* g0    = (const float*)d_in[7];
    const float* beta0 = (const float*)d_in[8];
    const float* g1    = (const float*)d_in[9];
    const float* beta1 = (const float*)d_in[10];
    float* out = (float*)d_out;

    const int N = NN, E = NE;

    // ---- workspace carve (~231 MB; proven budget >= 268 MB)
    char* ws = (char*)d_ws;
    auto alloc_b = [&](size_t bytes) {
        void* p = (void*)ws;
        ws += ((bytes + 255) / 256) * 256;
        return p;
    };
    float* norm_src = (float*)alloc_b((size_t)N * 4);
    float* norm_dst = (float*)alloc_b((size_t)N * 4);
    int*   row_ptr  = (int*)alloc_b((size_t)(N + 1) * 4);
    int*   csr_src  = (int*)alloc_b((size_t)E * 4);
    float* bnpart   = (float*)alloc_b((size_t)STAT_ROWS * 512 * 4);   // 5.44 MB per-block partials
    float* bnred    = (float*)alloc_b((size_t)STAT_NCH * 512 * 4);    // 172 KB chunk partials
    float* bn_a0    = (float*)alloc_b(256 * 4);
    float* bn_b0    = (float*)alloc_b(256 * 4);
    float* bn_a1    = (float*)alloc_b(256 * 4);
    float* bn_b1    = (float*)alloc_b(256 * 4);
    unsigned short* Wt0 = (unsigned short*)alloc_b((size_t)256 * 128 * 2);
    unsigned short* Wt1 = (unsigned short*)alloc_b((size_t)256 * 256 * 2);
    unsigned short* Wt2 = (unsigned short*)alloc_b((size_t)64 * 256 * 2);
    void* B1 = alloc_b((size_t)N * 512);   // N x 256 bf16 OR N x 40 f32
    void* B2 = alloc_b((size_t)N * 512);
    unsigned short* featb = (unsigned short*)alloc_b((size_t)N * F_IN * 2);

    unsigned short* B1b = (unsigned short*)B1;
    unsigned short* B2b = (unsigned short*)B2;
    float*          B1f = (float*)B1;

    // CSR-build scratch aliased at head of B1 (dead before fused0 writes B1)
    int* cnt_src  = (int*)B1;
    int* cnt_dst  = cnt_src + N;
    int* fill     = cnt_dst + N;
    int* local    = fill + N;
    int* partials = local + N;

    // ---- CSR build + norms + weight prep + feat cast (pre-scaled by norm_src)
    hipMemsetAsync(cnt_src, 0, ((size_t)4 * N + 1024) * 4, stream);
    count_kernel<<<(E + 255) / 256, 256, 0, stream>>>(src, dst, cnt_src, cnt_dst, E);
    norm_kernel<<<(N + 255) / 256, 256, 0, stream>>>(cnt_src, cnt_dst, norm_src, norm_dst, N);
    scan_block_kernel<<<SCAN_B, 256, 0, stream>>>(cnt_dst, local, partials, N);
    scan_partials_kernel<<<1, 1024, 0, stream>>>(partials, SCAN_B);
    scan_add_kernel<<<(N + 255) / 256, 256, 0, stream>>>(local, partials, row_ptr, N);
    fill_kernel<<<(E + 255) / 256, 256, 0, stream>>>(src, dst, row_ptr, fill, csr_src, E);
    wt_kernel<128, 256, 256><<<(256 * 128 + 255) / 256, 256, 0, stream>>>(W0, Wt0);
    wt_kernel<256, 256, 256><<<(256 * 256 + 255) / 256, 256, 0, stream>>>(W1, Wt1);
    wt_kernel<256, 40, 64><<<(64 * 256 + 255) / 256, 256, 0, stream>>>(W2, Wt2);
    cast_feat_kernel<<<((unsigned)N * (F_IN / 4) + 255) / 256, 256, 0, stream>>>(feat, norm_src, featb);

    // ---- layer 0: fused gather(sum) + GEMM0 (x norm_dst, stats) featb -> B1
    fused_gather_gemm<128, 4, 4, 4, false, false><<<GB64, 256, 0, stream>>>(
        featb, row_ptr, csr_src, nullptr, nullptr, Wt0, nullptr, norm_dst, nullptr, B1, bnpart, N);
    stat_reduce_kernel<<<STAT_NCH, 512, 0, stream>>>(bnpart, bnred);
    bn_finalize2_kernel<<<1, 256, 0, stream>>>(bnred, g0, beta0, bn_a0, bn_b0);

    // ---- layer 1: fused gather(BN0+ReLU+norm_src) + GEMM1 (x norm_dst, stats) B1 -> B2
    fused_gather_gemm<256, 4, 4, 4, true, false><<<GB64, 256, 0, stream>>>(
        B1b, row_ptr, csr_src, bn_a0, bn_b0, Wt1, norm_src, norm_dst, nullptr, B2, bnpart, N);
    stat_reduce_kernel<<<STAT_NCH, 512, 0, stream>>>(bnpart, bnred);
    bn_finalize2_kernel<<<1, 256, 0, stream>>>(bnred, g1, beta1, bn_a1, bn_b1);

    // ---- layer 2 (project-first): gemm2 (BN1+ReLU on A, x norm_src) B2 -> B1f (N x 40 f32),
    //      then narrow gather (sum, x norm_dst + b2) -> out. 160B/edge vs 512B/edge fused.
    gemm2_kernel<<<GB128, 256, 0, stream>>>(B2b, Wt2, norm_src, bn_a1, bn_b1, B1f, N);
    {
        unsigned total = (unsigned)N * (F_OUT / 4);
        gather_final_kernel<<<(total + 255) / 256, 256, 0, stream>>>(
            B1f, row_ptr, csr_src, norm_dst, b2, out, N);
    }
}

// Round 5
// 761.548 us; speedup vs baseline: 1.0766x; 1.0040x over previous
//
#include <hip/hip_runtime.h>

#define NN 170000
#define NE 1200000
#define F_IN 128
#define F_HID 256
#define F_OUT 40
#define BN_EPS 1e-5f
#define SCAN_B ((NN + 255) / 256)
#define GB32 ((NN + 31) / 32)
#define GB128 ((NN + 127) / 128)
#define STAT_ROWS GB32                               // one stat row per block (WAVES_M=1)
#define STAT_CHUNK 32
#define STAT_NCH ((STAT_ROWS + STAT_CHUNK - 1) / STAT_CHUNK)

typedef __attribute__((ext_vector_type(8))) short short8;
typedef __attribute__((ext_vector_type(4))) float f32x4;
typedef __attribute__((ext_vector_type(4))) unsigned short us4;
typedef __attribute__((ext_vector_type(4))) unsigned int u32x4;

// ---------------- bf16 helpers (manual, RNE) ----------------
__device__ __forceinline__ float b2f(unsigned short u) {
    union { unsigned x; float f; } c; c.x = ((unsigned)u) << 16; return c.f;
}
__device__ __forceinline__ unsigned short f2b(float f) {
    union { float f; unsigned x; } c; c.f = f;
    unsigned r = (c.x + 0x7FFFu + ((c.x >> 16) & 1u)) >> 16;
    return (unsigned short)r;
}
// BN+ReLU two packed bf16 lanes of one uint
__device__ __forceinline__ unsigned bn2(unsigned u, float a0, float b0, float a1, float b1) {
    float lo = b2f((unsigned short)(u & 0xffffu));
    float hi = b2f((unsigned short)(u >> 16));
    lo = fmaxf(lo * a0 + b0, 0.0f);
    hi = fmaxf(hi * a1 + b1, 0.0f);
    return (unsigned)f2b(lo) | ((unsigned)f2b(hi) << 16);
}

// 16B of bf16 (8 vals) accumulate into f32[8]
__device__ __forceinline__ void agg_sum(const u32x4& v, float (&aa)[8]) {
    aa[0] += b2f((unsigned short)(v.x & 0xffffu)); aa[1] += b2f((unsigned short)(v.x >> 16));
    aa[2] += b2f((unsigned short)(v.y & 0xffffu)); aa[3] += b2f((unsigned short)(v.y >> 16));
    aa[4] += b2f((unsigned short)(v.z & 0xffffu)); aa[5] += b2f((unsigned short)(v.z >> 16));
    aa[6] += b2f((unsigned short)(v.w & 0xffffu)); aa[7] += b2f((unsigned short)(v.w >> 16));
}
// fused BN+ReLU+norm_src per neighbor (f32), then accumulate
__device__ __forceinline__ void agg_fuse(const u32x4& v, float ns,
        const f32x4& ca0, const f32x4& ca1, const f32x4& cb0, const f32x4& cb1, float (&aa)[8]) {
    aa[0] += fmaxf(fmaf(b2f((unsigned short)(v.x & 0xffffu)), ca0.x, cb0.x), 0.f) * ns;
    aa[1] += fmaxf(fmaf(b2f((unsigned short)(v.x >> 16)),     ca0.y, cb0.y), 0.f) * ns;
    aa[2] += fmaxf(fmaf(b2f((unsigned short)(v.y & 0xffffu)), ca0.z, cb0.z), 0.f) * ns;
    aa[3] += fmaxf(fmaf(b2f((unsigned short)(v.y >> 16)),     ca0.w, cb0.w), 0.f) * ns;
    aa[4] += fmaxf(fmaf(b2f((unsigned short)(v.z & 0xffffu)), ca1.x, cb1.x), 0.f) * ns;
    aa[5] += fmaxf(fmaf(b2f((unsigned short)(v.z >> 16)),     ca1.y, cb1.y), 0.f) * ns;
    aa[6] += fmaxf(fmaf(b2f((unsigned short)(v.w & 0xffffu)), ca1.z, cb1.z), 0.f) * ns;
    aa[7] += fmaxf(fmaf(b2f((unsigned short)(v.w >> 16)),     ca1.w, cb1.w), 0.f) * ns;
}

// ---------------- CSR construction ----------------
__global__ void count_kernel(const int* __restrict__ src, const int* __restrict__ dst,
                             int* __restrict__ cnt_src, int* __restrict__ cnt_dst, int E) {
    int e = blockIdx.x * blockDim.x + threadIdx.x;
    if (e < E) {
        atomicAdd(&cnt_src[src[e]], 1);
        atomicAdd(&cnt_dst[dst[e]], 1);
    }
}

__global__ void norm_kernel(const int* __restrict__ cnt_src, const int* __restrict__ cnt_dst,
                            float* __restrict__ norm_src, float* __restrict__ norm_dst, int N) {
    int i = blockIdx.x * blockDim.x + threadIdx.x;
    if (i < N) {
        norm_src[i] = rsqrtf((float)max(cnt_src[i], 1));
        norm_dst[i] = rsqrtf((float)max(cnt_dst[i], 1));
    }
}

__global__ void scan_block_kernel(const int* __restrict__ cnt, int* __restrict__ local,
                                  int* __restrict__ partials, int N) {
    __shared__ int s[256];
    int t = threadIdx.x;
    int idx = blockIdx.x * 256 + t;
    int v = (idx < N) ? cnt[idx] : 0;
    s[t] = v;
    __syncthreads();
    #pragma unroll
    for (int off = 1; off < 256; off <<= 1) {
        int x = (t >= off) ? s[t - off] : 0;
        __syncthreads();
        s[t] += x;
        __syncthreads();
    }
    if (idx < N) local[idx] = s[t] - v;
    if (t == 255) partials[blockIdx.x] = s[t];
}

__global__ void scan_partials_kernel(int* __restrict__ partials, int B) {
    __shared__ int s[1024];
    int t = threadIdx.x;
    int v = (t < B) ? partials[t] : 0;
    s[t] = v;
    __syncthreads();
    #pragma unroll
    for (int off = 1; off < 1024; off <<= 1) {
        int x = (t >= off) ? s[t - off] : 0;
        __syncthreads();
        s[t] += x;
        __syncthreads();
    }
    if (t < B) partials[t] = s[t] - v;
}

__global__ void scan_add_kernel(const int* __restrict__ local, const int* __restrict__ partials,
                                int* __restrict__ row_ptr, int N) {
    int idx = blockIdx.x * blockDim.x + threadIdx.x;
    if (idx < N) row_ptr[idx] = local[idx] + partials[idx >> 8];
    if (idx == 0) row_ptr[N] = NE;
}

__global__ void fill_kernel(const int* __restrict__ src, const int* __restrict__ dst,
                            const int* __restrict__ row_ptr, int* __restrict__ fill,
                            int* __restrict__ csr_src, int E) {
    int e = blockIdx.x * blockDim.x + threadIdx.x;
    if (e < E) {
        int d = dst[e];
        int pos = row_ptr[d] + atomicAdd(&fill[d], 1);
        csr_src[pos] = src[e];
    }
}

// ---------------- feat f32 -> bf16, pre-scaled by norm_src[row] ----------------
__global__ void cast_feat_kernel(const float* __restrict__ feat, const float* __restrict__ norm_src,
                                 unsigned short* __restrict__ featb) {
    unsigned idx = blockIdx.x * blockDim.x + threadIdx.x;
    if (idx >= (unsigned)NN * (F_IN / 4)) return;
    float ns = norm_src[idx / (F_IN / 4)];
    f32x4 v = __builtin_nontemporal_load((const f32x4*)(feat + (size_t)idx * 4));
    us4 o; o.x = f2b(v.x * ns); o.y = f2b(v.y * ns); o.z = f2b(v.z * ns); o.w = f2b(v.w * ns);
    *(us4*)(featb + (size_t)idx * 4) = o;
}

// ---------------- weight transpose+cast: W[K][M] f32 -> Wt[MP][K] bf16 (zero-pad m>=M) ----
template<int K, int M, int MP>
__global__ void wt_kernel(const float* __restrict__ W, unsigned short* __restrict__ Wt) {
    int idx = blockIdx.x * blockDim.x + threadIdx.x;
    if (idx >= MP * K) return;
    int m = idx / K, k = idx % K;
    float v = (m < M) ? W[(size_t)k * M + m] : 0.0f;
    Wt[idx] = f2b(v);
}

// ---------------- BN stats: tree reduce of per-block partials ----------------
__global__ void stat_reduce_kernel(const float* __restrict__ part, float* __restrict__ red) {
    int c = threadIdx.x;                 // 0..511
    int ch = blockIdx.x;
    int r0 = ch * STAT_CHUNK;
    int r1 = min(r0 + STAT_CHUNK, STAT_ROWS);
    float s = 0.f;
    for (int r = r0; r < r1; r++) s += part[(size_t)r * 512 + c];
    red[ch * 512 + c] = s;
}

__global__ void bn_finalize2_kernel(const float* __restrict__ red,
                                    const float* __restrict__ gamma, const float* __restrict__ beta,
                                    float* __restrict__ a, float* __restrict__ b) {
    int c = threadIdx.x;                 // 0..255
    float sum = 0.f, sumsq = 0.f;
    for (int ch = 0; ch < STAT_NCH; ch++) {
        sum   += red[ch * 512 + c];
        sumsq += red[ch * 512 + 256 + c];
    }
    float invN = 1.0f / (float)NN;
    float mean = sum * invN;
    float var = sumsq * invN - mean * mean;
    float inv = rsqrtf(var + BN_EPS);
    float ac = inv * gamma[c];
    a[c] = ac;
    b[c] = beta[c] - mean * ac;
}

// ---------------- fused gather + MFMA GEMM (GraphConv layers 0 and 1) ----------------
// R12 occupancy round: the fused gather is latency-bound; throughput ~ resident waves x
// loads-in-flight/wave. R4 proved raising the per-lane factor (unroll-4) LOSES (VGPR 80->96,
// occ 29->20%, 210->232us); the standalone gather (16 VGPR, no LDS, 74% occ) hits 3.2 TB/s
// vs our 2.0. So: unroll-2 (reverted) + BM 64->32 (LDS 32->16/8 KB, acc 64->32 VGPR) to
// double block residency and halve each wave's serial gather chain (8 nodes/wave).
// MFMA: WAVES_N=4, each wave computes all BM rows x its 64-col slice from XOR-swizzled LDS.
template<int F, int WM_T, int WN_T, int WAVES_N, bool FUSE>
__global__ __launch_bounds__(256) void fused_gather_gemm(
        const unsigned short* __restrict__ h,          // N x F bf16 input rows
        const int* __restrict__ row_ptr, const int* __restrict__ csr_src,
        const float* __restrict__ bna, const float* __restrict__ bnb,
        const unsigned short* __restrict__ Wt,         // [MP][F] bf16
        const float* __restrict__ norm_src, const float* __restrict__ norm_dst,
        void* __restrict__ C, float* __restrict__ opart, int N) {
    constexpr int WAVES_M = 4 / WAVES_N;
    constexpr int BM = WM_T * 16 * WAVES_M;           // 32 for WAVES_N=4, WM_T=2
    constexpr int LPN = F / 8;        // lanes per node (16B slices)
    constexpr int NPW = 64 / LPN;     // nodes gathered concurrently per wave
    constexpr int NPB = BM / 4;       // nodes gathered per wave total
    __shared__ unsigned short As[BM * F];

    const int lane = threadIdx.x & 63;
    const int wave = threadIdx.x >> 6;
    const int r0 = blockIdx.x * BM;

    // ---- phase 1: gather NPB nodes per wave into As ----
    {
        const int sub = lane / LPN;
        const int cl = lane % LPN;
        f32x4 ca0 = {0,0,0,0}, ca1 = {0,0,0,0}, cb0 = {0,0,0,0}, cb1 = {0,0,0,0};
        if (FUSE) {
            ca0 = *(const f32x4*)(bna + cl * 8);
            ca1 = *(const f32x4*)(bna + cl * 8 + 4);
            cb0 = *(const f32x4*)(bnb + cl * 8);
            cb1 = *(const f32x4*)(bnb + cl * 8 + 4);
        }
        #pragma unroll
        for (int g = 0; g < NPB / NPW; g++) {
            int nl = wave * NPB + g * NPW + sub;
            int node = r0 + nl;
            float aa[8] = {0.f, 0.f, 0.f, 0.f, 0.f, 0.f, 0.f, 0.f};
            int beg = 0, end = 0;
            if (node < N) { beg = row_ptr[node]; end = row_ptr[node + 1]; }
            int e = beg;
            for (; e + 2 <= end; e += 2) {
                int s0 = csr_src[e], s1 = csr_src[e + 1];
                u32x4 v0 = *(const u32x4*)(h + (size_t)s0 * F + cl * 8);
                u32x4 v1 = *(const u32x4*)(h + (size_t)s1 * F + cl * 8);
                if (FUSE) {
                    float n0 = norm_src[s0], n1 = norm_src[s1];
                    agg_fuse(v0, n0, ca0, ca1, cb0, cb1, aa);
                    agg_fuse(v1, n1, ca0, ca1, cb0, cb1, aa);
                } else {
                    agg_sum(v0, aa); agg_sum(v1, aa);
                }
            }
            if (e < end) {
                int s0 = csr_src[e];
                u32x4 v0 = *(const u32x4*)(h + (size_t)s0 * F + cl * 8);
                if (FUSE) agg_fuse(v0, norm_src[s0], ca0, ca1, cb0, cb1, aa);
                else      agg_sum(v0, aa);
            }
            u32x4 d;
            d.x = (unsigned)f2b(aa[0]) | ((unsigned)f2b(aa[1]) << 16);
            d.y = (unsigned)f2b(aa[2]) | ((unsigned)f2b(aa[3]) << 16);
            d.z = (unsigned)f2b(aa[4]) | ((unsigned)f2b(aa[5]) << 16);
            d.w = (unsigned)f2b(aa[6]) | ((unsigned)f2b(aa[7]) << 16);
            unsigned off = ((unsigned)(nl * (F * 2) + cl * 16)) ^ (((unsigned)nl & 7u) << 4);
            *(u32x4*)((char*)As + off) = d;
        }
    }
    __syncthreads();

    // ---- phase 2: MFMA As (LDS) x Wt (L2) ----
    const int quad = lane >> 4, l15 = lane & 15;
    const int wr = wave / WAVES_N, wc = wave % WAVES_N;
    const int wmb = wr * WM_T * 16;
    const int wnb = wc * WN_T * 16;

    const unsigned short* bptr[WN_T];
    #pragma unroll
    for (int j = 0; j < WN_T; j++)
        bptr[j] = Wt + (size_t)(wnb + j * 16 + l15) * F + quad * 8;

    f32x4 acc[WM_T][WN_T] = {};
    #pragma unroll
    for (int kk = 0; kk < F; kk += 32) {
        short8 af[WM_T], bf[WN_T];
        #pragma unroll
        for (int i = 0; i < WM_T; i++) {
            int row = wmb + i * 16 + l15;
            unsigned off = ((unsigned)(row * (F * 2) + (kk + quad * 8) * 2)) ^ (((unsigned)row & 7u) << 4);
            af[i] = *(const short8*)((const char*)As + off);
        }
        #pragma unroll
        for (int j = 0; j < WN_T; j++)
            bf[j] = *(const short8*)(bptr[j] + kk);
        #pragma unroll
        for (int i = 0; i < WM_T; i++)
            #pragma unroll
            for (int j = 0; j < WN_T; j++)
                acc[i][j] = __builtin_amdgcn_mfma_f32_16x16x32_bf16(af[i], bf[j], acc[i][j], 0, 0, 0);
    }

    // ---- epilogue: C/D layout col=lane&15, row=quad*4+reg ----
    float s[WN_T] = {}, ss[WN_T] = {};
    #pragma unroll
    for (int i = 0; i < WM_T; i++) {
        #pragma unroll
        for (int r = 0; r < 4; r++) {
            int row = r0 + wmb + i * 16 + quad * 4 + r;
            if (row >= N) continue;
            float nd = norm_dst[row];
            #pragma unroll
            for (int j = 0; j < WN_T; j++) {
                float v = acc[i][j][r] * nd;
                int col = wnb + j * 16 + l15;
                s[j] += v; ss[j] += v * v;
                ((unsigned short*)C)[(size_t)row * F_HID + col] = f2b(v);
            }
        }
    }
    #pragma unroll
    for (int j = 0; j < WN_T; j++) {
        float t = s[j], t2 = ss[j];
        t  += __shfl_xor(t, 16);  t  += __shfl_xor(t, 32);
        t2 += __shfl_xor(t2, 16); t2 += __shfl_xor(t2, 32);
        if (quad == 0) {
            int col = wnb + j * 16 + l15;
            size_t prow = (size_t)(blockIdx.x * WAVES_M + wr) * 512;
            opart[prow + col] = t;
            opart[prow + 256 + col] = t2;
        }
    }
}

// ---------------- layer-2 projection GEMM: barrier-free, direct-register ----------------
// x = norm_src .* relu(bn1(h1)); y_pre = x @ W2  (N x 40, f32). BN+ReLU applied on A-fragments,
// norm_src as epilogue row-scale (commutes with @W2 by linearity). No LDS, no barriers.
__global__ __launch_bounds__(256, 3) void gemm2_kernel(const unsigned short* __restrict__ A,
                                                       const unsigned short* __restrict__ Wt,
                                                       const float* __restrict__ norm_src,
                                                       const float* __restrict__ bna,
                                                       const float* __restrict__ bnb,
                                                       float* __restrict__ C, int N) {
    constexpr int K = 256, WM_T = 2, WN_T = 4;
    const int lane = threadIdx.x & 63;
    const int wave = threadIdx.x >> 6;
    const int quad = lane >> 4, l15 = lane & 15;
    const int r0 = blockIdx.x * 128;
    const int wmb = wave * WM_T * 16;

    const unsigned short* aptr[WM_T];
    #pragma unroll
    for (int i = 0; i < WM_T; i++) {
        int gr = r0 + wmb + i * 16 + l15;
        if (gr > N - 1) gr = N - 1;
        aptr[i] = A + (size_t)gr * K + quad * 8;
    }
    const unsigned short* bptr[WN_T];
    #pragma unroll
    for (int j = 0; j < WN_T; j++)
        bptr[j] = Wt + (size_t)(j * 16 + l15) * K + quad * 8;

    f32x4 acc[WM_T][WN_T] = {};
    #pragma unroll
    for (int kk = 0; kk < K; kk += 32) {
        int kb = kk + quad * 8;
        const f32x4 a0 = *(const f32x4*)(bna + kb);
        const f32x4 a1 = *(const f32x4*)(bna + kb + 4);
        const f32x4 s0 = *(const f32x4*)(bnb + kb);
        const f32x4 s1 = *(const f32x4*)(bnb + kb + 4);
        short8 af[WM_T], bf[WN_T];
        #pragma unroll
        for (int i = 0; i < WM_T; i++) {
            u32x4 u = *(const u32x4*)(aptr[i] + kk);
            u.x = bn2(u.x, a0.x, s0.x, a0.y, s0.y);
            u.y = bn2(u.y, a0.z, s0.z, a0.w, s0.w);
            u.z = bn2(u.z, a1.x, s1.x, a1.y, s1.y);
            u.w = bn2(u.w, a1.z, s1.z, a1.w, s1.w);
            af[i] = *(short8*)&u;
        }
        #pragma unroll
        for (int j = 0; j < WN_T; j++)
            bf[j] = *(const short8*)(bptr[j] + kk);
        #pragma unroll
        for (int i = 0; i < WM_T; i++)
            #pragma unroll
            for (int j = 0; j < WN_T; j++)
                acc[i][j] = __builtin_amdgcn_mfma_f32_16x16x32_bf16(af[i], bf[j], acc[i][j], 0, 0, 0);
    }

    #pragma unroll
    for (int i = 0; i < WM_T; i++) {
        #pragma unroll
        for (int r = 0; r < 4; r++) {
            int row = r0 + wmb + i * 16 + quad * 4 + r;
            if (row >= N) continue;
            float ns = norm_src[row];
            #pragma unroll
            for (int j = 0; j < WN_T; j++) {
                int col = j * 16 + l15;
                if (col < F_OUT)
                    C[(size_t)row * F_OUT + col] = acc[i][j][r] * ns;
            }
        }
    }
}

// ---------------- final gather: f32 in (width 40, pre-scaled by norm_src) + nd + bias ----------
__global__ void gather_final_kernel(const float* __restrict__ h, const int* __restrict__ row_ptr,
                                    const int* __restrict__ csr_src,
                                    const float* __restrict__ norm_dst, const float* __restrict__ bias,
                                    float* __restrict__ out, int N) {
    constexpr int TPN = F_OUT / 4;
    unsigned idx = blockIdx.x * blockDim.x + threadIdx.x;
    if (idx >= (unsigned)N * TPN) return;
    unsigned node = idx / TPN;
    unsigned g = idx % TPN;
    int beg = row_ptr[node], end = row_ptr[node + 1];
    float ax0 = 0.f, ay0 = 0.f, az0 = 0.f, aw0 = 0.f;
    float ax1 = 0.f, ay1 = 0.f, az1 = 0.f, aw1 = 0.f;
    int e = beg;
    for (; e + 2 <= end; e += 2) {
        int s0 = csr_src[e], s1 = csr_src[e + 1];
        const f32x4 v0 = *(const f32x4*)(h + (size_t)s0 * F_OUT + g * 4);
        const f32x4 v1 = *(const f32x4*)(h + (size_t)s1 * F_OUT + g * 4);
        ax0 += v0.x; ay0 += v0.y; az0 += v0.z; aw0 += v0.w;
        ax1 += v1.x; ay1 += v1.y; az1 += v1.z; aw1 += v1.w;
    }
    if (e < end) {
        int s0 = csr_src[e];
        const f32x4 v0 = *(const f32x4*)(h + (size_t)s0 * F_OUT + g * 4);
        ax0 += v0.x; ay0 += v0.y; az0 += v0.z; aw0 += v0.w;
    }
    float nd = norm_dst[node];
    const f32x4 b = *(const f32x4*)(bias + g * 4);
    f32x4 r;
    r.x = (ax0 + ax1) * nd + b.x; r.y = (ay0 + ay1) * nd + b.y;
    r.z = (az0 + az1) * nd + b.z; r.w = (aw0 + aw1) * nd + b.w;
    __builtin_nontemporal_store(r, (f32x4*)(out + (size_t)node * F_OUT + g * 4));
}

extern "C" void kernel_launch(void* const* d_in, const int* in_sizes, int n_in,
                              void* d_out, int out_size, void* d_ws, size_t ws_size,
                              hipStream_t stream) {
    const float* feat  = (const float*)d_in[0];
    const int*   src   = (const int*)d_in[1];
    const int*   dst   = (const int*)d_in[2];
    const float* W0    = (const float*)d_in[3];
    const float* W1    = (const float*)d_in[4];
    const float* W2    = (const float*)d_in[5];
    const float* b2    = (const float*)d_in[6];
    const float* g0    = (const float*)d_in[7];
    const float* beta0 = (const float*)d_in[8];
    const float* g1    = (const float*)d_in[9];
    const float* beta1 = (const float*)d_in[10];
    float* out = (float*)d_out;

    const int N = NN, E = NE;

    // ---- workspace carve (~237 MB; proven budget >= 268 MB)
    char* ws = (char*)d_ws;
    auto alloc_b = [&](size_t bytes) {
        void* p = (void*)ws;
        ws += ((bytes + 255) / 256) * 256;
        return p;
    };
    float* norm_src = (float*)alloc_b((size_t)N * 4);
    float* norm_dst = (float*)alloc_b((size_t)N * 4);
    int*   row_ptr  = (int*)alloc_b((size_t)(N + 1) * 4);
    int*   csr_src  = (int*)alloc_b((size_t)E * 4);
    float* bnpart   = (float*)alloc_b((size_t)STAT_ROWS * 512 * 4);   // 10.9 MB per-block partials
    float* bnred    = (float*)alloc_b((size_t)STAT_NCH * 512 * 4);    // ~340 KB chunk partials
    float* bn_a0    = (float*)alloc_b(256 * 4);
    float* bn_b0    = (float*)alloc_b(256 * 4);
    float* bn_a1    = (float*)alloc_b(256 * 4);
    float* bn_b1    = (float*)alloc_b(256 * 4);
    unsigned short* Wt0 = (unsigned short*)alloc_b((size_t)256 * 128 * 2);
    unsigned short* Wt1 = (unsigned short*)alloc_b((size_t)256 * 256 * 2);
    unsigned short* Wt2 = (unsigned short*)alloc_b((size_t)64 * 256 * 2);
    void* B1 = alloc_b((size_t)N * 512);   // N x 256 bf16 OR N x 40 f32
    void* B2 = alloc_b((size_t)N * 512);
    unsigned short* featb = (unsigned short*)alloc_b((size_t)N * F_IN * 2);

    unsigned short* B1b = (unsigned short*)B1;
    unsigned short* B2b = (unsigned short*)B2;
    float*          B1f = (float*)B1;

    // CSR-build scratch aliased at head of B1 (dead before fused0 writes B1)
    int* cnt_src  = (int*)B1;
    int* cnt_dst  = cnt_src + N;
    int* fill     = cnt_dst + N;
    int* local    = fill + N;
    int* partials = local + N;

    // ---- CSR build + norms + weight prep + feat cast (pre-scaled by norm_src)
    hipMemsetAsync(cnt_src, 0, ((size_t)4 * N + 1024) * 4, stream);
    count_kernel<<<(E + 255) / 256, 256, 0, stream>>>(src, dst, cnt_src, cnt_dst, E);
    norm_kernel<<<(N + 255) / 256, 256, 0, stream>>>(cnt_src, cnt_dst, norm_src, norm_dst, N);
    scan_block_kernel<<<SCAN_B, 256, 0, stream>>>(cnt_dst, local, partials, N);
    scan_partials_kernel<<<1, 1024, 0, stream>>>(partials, SCAN_B);
    scan_add_kernel<<<(N + 255) / 256, 256, 0, stream>>>(local, partials, row_ptr, N);
    fill_kernel<<<(E + 255) / 256, 256, 0, stream>>>(src, dst, row_ptr, fill, csr_src, E);
    wt_kernel<128, 256, 256><<<(256 * 128 + 255) / 256, 256, 0, stream>>>(W0, Wt0);
    wt_kernel<256, 256, 256><<<(256 * 256 + 255) / 256, 256, 0, stream>>>(W1, Wt1);
    wt_kernel<256, 40, 64><<<(64 * 256 + 255) / 256, 256, 0, stream>>>(W2, Wt2);
    cast_feat_kernel<<<((unsigned)N * (F_IN / 4) + 255) / 256, 256, 0, stream>>>(feat, norm_src, featb);

    // ---- layer 0: fused gather(sum) + GEMM0 (x norm_dst, stats) featb -> B1
    fused_gather_gemm<128, 2, 4, 4, false><<<GB32, 256, 0, stream>>>(
        featb, row_ptr, csr_src, nullptr, nullptr, Wt0, nullptr, norm_dst, B1, bnpart, N);
    stat_reduce_kernel<<<STAT_NCH, 512, 0, stream>>>(bnpart, bnred);
    bn_finalize2_kernel<<<1, 256, 0, stream>>>(bnred, g0, beta0, bn_a0, bn_b0);

    // ---- layer 1: fused gather(BN0+ReLU+norm_src) + GEMM1 (x norm_dst, stats) B1 -> B2
    fused_gather_gemm<256, 2, 4, 4, true><<<GB32, 256, 0, stream>>>(
        B1b, row_ptr, csr_src, bn_a0, bn_b0, Wt1, norm_src, norm_dst, B2, bnpart, N);
    stat_reduce_kernel<<<STAT_NCH, 512, 0, stream>>>(bnpart, bnred);
    bn_finalize2_kernel<<<1, 256, 0, stream>>>(bnred, g1, beta1, bn_a1, bn_b1);

    // ---- layer 2 (project-first): gemm2 (BN1+ReLU on A, x norm_src) B2 -> B1f (N x 40 f32),
    //      then narrow gather (sum, x norm_dst + b2) -> out. 160B/edge vs 512B/edge fused.
    gemm2_kernel<<<GB128, 256, 0, stream>>>(B2b, Wt2, norm_src, bn_a1, bn_b1, B1f, N);
    {
        unsigned total = (unsigned)N * (F_OUT / 4);
        gather_final_kernel<<<(total + 255) / 256, 256, 0, stream>>>(
            B1f, row_ptr, csr_src, norm_dst, b2, out, N);
    }
}